// Round 4
// baseline (203.192 us; speedup 1.0000x reference)
//
#include <hip/hip_runtime.h>

// CTC batch cost (keras ctc_batch_cost semantics), forward only.
// B=512, T=512, C=128 (blank=127), L=32, S=65.
// One wave per batch element; lane s holds alpha[s]; lane 63 also carries
// state 64. Probability domain, 4-row composed updates, exact-pow2 rescale.
//
// Round-4 change: delete the LDS apparatus entirely. Identity
//   cls[i](lane) == cls[0](lane-i)
// means all 17 per-group q-values are lane-shifts (DPP wave_shr, zero-fill)
// of 4 per-lane loads P[r] = q(row t0+r, cls0(lane)). Zero-fill is exact:
// wherever the shifted value differs from the old q_blank gather (lanes
// s < i), it is multiplied by an alpha-sum that is identically zero.
// Per group: 4 scattered global loads (register-prefetched PFG=8 groups
// ahead), 13+8 DPP shifts, no LDS, no vmcnt asm, no bank conflicts.
// Rescale: per-group exact-pow2 via v_readlane exponent max (proven r3).

#define EPSF 1e-7f

constexpr int T_  = 512;
constexpr int C_  = 128;
constexpr int L_  = 32;
constexpr int NG  = 127;   // groups of 4 rows: rows 1..508
constexpr int PFG = 8;     // register prefetch depth (groups)

// lane j -> value of lane j-1; lane 0 -> 0.  (DPP wave_shr:1, bound_ctrl=0-fill)
__device__ __forceinline__ float wshr1(float x) {
    return __int_as_float(
        __builtin_amdgcn_mov_dpp(__float_as_int(x), 0x138, 0xf, 0xf, true));
}

__launch_bounds__(64)
__global__ void ctc_loss_kernel(const int* __restrict__ y_true,
                                const float* __restrict__ y_pred,
                                float* __restrict__ out) {
    const int b    = blockIdx.x;
    const int lane = threadIdx.x;

    const float* bb  = y_pred + (size_t)b * T_ * C_;
    const int*   lbl = y_true + b * L_;

    // Per-lane class for state s = lane, and skip flags for states s-0..s-6.
    int   cls0;
    float sg[7];
    {
        int c0 = C_ - 1;
        if (lane >= 1 && (lane & 1)) c0 = lbl[(lane - 1) >> 1];
        cls0 = c0;
#pragma unroll
        for (int i = 0; i < 7; ++i) {
            const int v = lane - i;
            float s = 0.f;
            if (v >= 3 && (v & 1)) {
                const int c = lbl[(v - 1) >> 1];
                if (c != lbl[((v - 1) >> 1) - 1]) s = 1.f;
            }
            sg[i] = s;
        }
    }

    // t=0 init (prob domain): states 0,1 = q0[cls]+eps, rest 0.
    float a       = (lane < 2) ? (bb[cls0] + EPSF) : 0.f;
    float a64     = 0.f;   // state 64, meaningful on lane 63 only
    int   e_total = 0;     // accumulated log2 scale (exact integer)

    // Per-lane column pointer: q(row, cls0(lane)) for 4 consecutive rows.
    auto loadQ = [&](float (&Pk)[4], int g) {
        const float* r = bb + (size_t)(1 + 4 * g) * C_ + cls0;
        Pk[0] = r[0];
        Pk[1] = r[C_];
        Pk[2] = r[2 * C_];
        Pk[3] = r[3 * C_];
    };

    // Exponent sample of `a` at lanes 3,7,...,63. Positive floats: int-max of
    // bit patterns == bit pattern of float max; only the exponent is used.
    // 27 = biased exponent of the 1e-30 dead-sample guard.
    auto sample_eb = [&]() -> int {
        int mb = __builtin_amdgcn_readlane(__float_as_int(a), 3);
#pragma unroll
        for (int i = 1; i < 16; ++i) {
            const int v = __builtin_amdgcn_readlane(__float_as_int(a), 4 * i + 3);
            mb = (v > mb) ? v : mb;
        }
        const int eb = (int)((unsigned)mb >> 23);
        return (eb > 27) ? eb : 27;
    };

    // Exact pow2 rescale from a previously-sampled exponent.
    auto apply_scale = [&](int eb) {
        e_total += eb - 127;
        const float inv = __uint_as_float((unsigned)(254 - eb) << 23);  // 2^-e
        a   *= inv;
        a64 *= inv;
    };

    // Composed 4-step update (linear in alpha -> scaling commutes).
    // All cross-lane data via chained DPP wave_shr:1 (zero-fill).
    auto group4 = [&](const float (&P)[4]) {
        // Q pyramids: q0[i] = (q(row0, cls_i)+eps) etc., via shifts of P+eps.
        float q0[7];
        q0[0] = P[0] + EPSF;
#pragma unroll
        for (int i = 1; i < 7; ++i) q0[i] = wshr1(q0[i - 1]);
        float q1[5];
        q1[0] = P[1] + EPSF;
#pragma unroll
        for (int i = 1; i < 5; ++i) q1[i] = wshr1(q1[i - 1]);
        float q2[3];
        q2[0] = P[2] + EPSF;
#pragma unroll
        for (int i = 1; i < 3; ++i) q2[i] = wshr1(q2[i - 1]);
        float q3[2];
        q3[0] = P[3] + EPSF;
        q3[1] = wshr1(q3[0]);

        float A[9];
        A[0] = a;
#pragma unroll
        for (int i = 1; i <= 8; ++i) A[i] = wshr1(A[i - 1]);

        float B[7];
#pragma unroll
        for (int i = 0; i <= 6; ++i)
            B[i] = (A[i] + A[i + 1] + sg[i] * A[i + 2]) * q0[i];
        float Cc[5];
#pragma unroll
        for (int i = 0; i <= 4; ++i)
            Cc[i] = (B[i] + B[i + 1] + sg[i] * B[i + 2]) * q1[i];
        float D[3];
#pragma unroll
        for (int i = 0; i <= 2; ++i)
            D[i] = (Cc[i] + Cc[i + 1] + sg[i] * Cc[i + 2]) * q2[i];

        // state-64 chain (valid on lane 63; harmless elsewhere)
        float z = a64;
        z = (z + A[0])  * q0[1];
        z = (z + B[0])  * q1[1];
        z = (z + Cc[0]) * q2[1];
        z = (z + D[0])  * q3[1];
        a64 = z;

        a = (D[0] + D[1] + sg[0] * D[2]) * q3[0];
    };

    // Prologue: prefetch PFG groups of 4 row-values into registers.
    float Q[PFG][4];
#pragma unroll
    for (int k = 0; k < PFG; ++k) loadQ(Q[k], k);

    int ebp = sample_eb();   // seed from t=0 alpha

    // Main loop: groups 0..111 (14 iterations), refill g+8 (groups 8..119).
    for (int g0 = 0; g0 < 112; g0 += PFG) {
#pragma unroll
        for (int k = 0; k < PFG; ++k) {
            group4(Q[k]);
            apply_scale(ebp);
            ebp = sample_eb();
            loadQ(Q[k], g0 + k + PFG);
        }
    }

    // Groups 112..119 (Q[0..7]); refill 120..126 into Q[0..6].
#pragma unroll
    for (int k = 0; k < PFG; ++k) {
        group4(Q[k]);
        apply_scale(ebp);
        ebp = sample_eb();
        if (k < 7) loadQ(Q[k], 120 + k);
    }

    // Tail-row gathers (rows 509..511), issued before the last block.
    float qo[3];
#pragma unroll
    for (int r = 0; r < 3; ++r) qo[r] = bb[(size_t)(509 + r) * C_ + cls0];

    // Groups 120..126 (Q[0..6]).
#pragma unroll
    for (int k = 0; k < 7; ++k) {
        group4(Q[k]);
        apply_scale(ebp);
        if (k < 6) ebp = sample_eb();
    }

    // Rows 509..511, single steps (3 rows: no rescale needed).
    // qb (blank-column value at state 63's predecessor) = wshr1(qo):
    // at lane 63 it equals q_row[cls0(62)] — bit-identical to the old gather.
#pragma unroll
    for (int r = 0; r < 3; ++r) {
        const float p1 = wshr1(a);
        const float p2 = wshr1(p1);
        const float qb = wshr1(qo[r]);
        const float anew = (a + p1 + sg[0] * p2) * (qo[r] + EPSF);
        a64 = (a64 + a) * (qb + EPSF);
        a = anew;
    }

    if (lane == 63) {
        out[b] = -(__logf(a + a64) + (float)e_total * 0.6931471805599453f);
    }
}

extern "C" void kernel_launch(void* const* d_in, const int* in_sizes, int n_in,
                              void* d_out, int out_size, void* d_ws, size_t ws_size,
                              hipStream_t stream) {
    const int*   y_true = (const int*)d_in[0];
    const float* y_pred = (const float*)d_in[1];
    float*       out    = (float*)d_out;

    const int B = out_size;   // output is [B,1]
    ctc_loss_kernel<<<B, 64, 0, stream>>>(y_true, y_pred, out);
}

// Round 5
// 194.828 us; speedup vs baseline: 1.0429x; 1.0429x over previous
//
#include <hip/hip_runtime.h>

// CTC batch cost (keras ctc_batch_cost semantics), forward only.
// B=512, T=512, C=128 (blank=127), L=32, S=65.
// One wave per batch element; lane s holds alpha[s]; lane 63 also carries
// state 64. Probability domain, 4-row composed updates, exact-pow2 rescale.
//
// Round-5 change: collapse the B/C/D shift-pyramid. Identity (same family
// as the r4 cls-collapse): A[i](l)=a(l-i), sg[i](l)=sg[0](l-i),
// q[i](l)=q[0](l-i)  =>  B[i](l)=B[0](l-i) exactly (incl. zero-fill), and
// recursively for C, D. So each of the 4 composed rows needs only its
// column-0 value:
//   x <- (x + x>>1 + sg0 * x>>2) * (P[r]+eps)          (>> = DPP wave_shr)
//   z <- (z + x_pre) * wshr1(P[r]+eps)                 (state-64 chain)
// Per-group VALU ~62 vs ~105. All retained values bit-identical to r4.
// Loads: 4 per-lane column loads/group, register-prefetched PFG=8 ahead.
// Rescale: per-group exact-pow2 via v_readlane exponent max (proven r3/r4).

#define EPSF 1e-7f

constexpr int T_  = 512;
constexpr int C_  = 128;
constexpr int L_  = 32;
constexpr int NG  = 127;   // groups of 4 rows: rows 1..508
constexpr int PFG = 8;     // register prefetch depth (groups)

// lane j -> value of lane j-1; lane 0 -> 0.  (DPP wave_shr:1, bound_ctrl=0-fill)
__device__ __forceinline__ float wshr1(float x) {
    return __int_as_float(
        __builtin_amdgcn_mov_dpp(__float_as_int(x), 0x138, 0xf, 0xf, true));
}

__launch_bounds__(64)
__global__ void ctc_loss_kernel(const int* __restrict__ y_true,
                                const float* __restrict__ y_pred,
                                float* __restrict__ out) {
    const int b    = blockIdx.x;
    const int lane = threadIdx.x;

    const float* bb  = y_pred + (size_t)b * T_ * C_;
    const int*   lbl = y_true + b * L_;

    // Per-lane class for state s = lane, and own-state skip flag sg0.
    int   cls0;
    float sg0;
    {
        int c0 = C_ - 1;
        if (lane >= 1 && (lane & 1)) c0 = lbl[(lane - 1) >> 1];
        cls0 = c0;
        float s = 0.f;
        if (lane >= 3 && (lane & 1)) {
            const int c = lbl[(lane - 1) >> 1];
            if (c != lbl[((lane - 1) >> 1) - 1]) s = 1.f;
        }
        sg0 = s;
    }

    // t=0 init (prob domain): states 0,1 = q0[cls]+eps, rest 0.
    float a       = (lane < 2) ? (bb[cls0] + EPSF) : 0.f;
    float a64     = 0.f;   // state 64, meaningful on lane 63 only
    int   e_total = 0;     // accumulated log2 scale (exact integer)

    // Per-lane column loads: q(row, cls0(lane)) for 4 consecutive rows.
    auto loadQ = [&](float (&Pk)[4], int g) {
        const float* r = bb + (size_t)(1 + 4 * g) * C_ + cls0;
        Pk[0] = r[0];
        Pk[1] = r[C_];
        Pk[2] = r[2 * C_];
        Pk[3] = r[3 * C_];
    };

    // Exponent sample of `a` at lanes 3,7,...,63. Positive floats: int-max of
    // bit patterns == bit pattern of float max; only the exponent is used.
    // 27 = biased exponent of the 1e-30 dead-sample guard.
    auto sample_eb = [&]() -> int {
        int mb = __builtin_amdgcn_readlane(__float_as_int(a), 3);
#pragma unroll
        for (int i = 1; i < 16; ++i) {
            const int v = __builtin_amdgcn_readlane(__float_as_int(a), 4 * i + 3);
            mb = (v > mb) ? v : mb;
        }
        const int eb = (int)((unsigned)mb >> 23);
        return (eb > 27) ? eb : 27;
    };

    // Exact pow2 rescale from a previously-sampled exponent.
    auto apply_scale = [&](int eb) {
        e_total += eb - 127;
        const float inv = __uint_as_float((unsigned)(254 - eb) << 23);  // 2^-e
        a   *= inv;
        a64 *= inv;
    };

    // Composed 4-row update, column-0 collapsed form. Bit-identical to the
    // full-pyramid version (see header).
    auto group4 = [&](const float (&P)[4]) {
        float x = a;
        float z = a64;
#pragma unroll
        for (int r = 0; r < 4; ++r) {
            const float q  = P[r] + EPSF;
            const float qs = wshr1(q);      // lane-1's column value (+eps)
            const float x1 = wshr1(x);
            const float x2 = wshr1(x1);
            z = (z + x) * qs;               // uses pre-update x
            x = (x + x1 + sg0 * x2) * q;
        }
        a   = x;
        a64 = z;
    };

    // Prologue: prefetch PFG groups of 4 row-values into registers.
    float Q[PFG][4];
#pragma unroll
    for (int k = 0; k < PFG; ++k) loadQ(Q[k], k);

    int ebp = sample_eb();   // seed from t=0 alpha

    // Main loop: groups 0..111 (14 iterations), refill g+8 (groups 8..119).
    for (int g0 = 0; g0 < 112; g0 += PFG) {
#pragma unroll
        for (int k = 0; k < PFG; ++k) {
            group4(Q[k]);
            apply_scale(ebp);
            ebp = sample_eb();
            loadQ(Q[k], g0 + k + PFG);
        }
    }

    // Groups 112..119 (Q[0..7]); refill 120..126 into Q[0..6].
#pragma unroll
    for (int k = 0; k < PFG; ++k) {
        group4(Q[k]);
        apply_scale(ebp);
        ebp = sample_eb();
        if (k < 7) loadQ(Q[k], 120 + k);
    }

    // Tail-row gathers (rows 509..511), issued before the last block.
    float qo[3];
#pragma unroll
    for (int r = 0; r < 3; ++r) qo[r] = bb[(size_t)(509 + r) * C_ + cls0];

    // Groups 120..126 (Q[0..6]).
#pragma unroll
    for (int k = 0; k < 7; ++k) {
        group4(Q[k]);
        apply_scale(ebp);
        if (k < 6) ebp = sample_eb();
    }

    // Rows 509..511, single steps (3 rows: no rescale needed).
    // qb (blank-column value for the state-64 chain) = wshr1(qo): at lane 63
    // it equals q_row[cls0(62)] = q_row[blank] — identical to prior rounds.
#pragma unroll
    for (int r = 0; r < 3; ++r) {
        const float p1 = wshr1(a);
        const float p2 = wshr1(p1);
        const float qb = wshr1(qo[r]);
        const float anew = (a + p1 + sg0 * p2) * (qo[r] + EPSF);
        a64 = (a64 + a) * (qb + EPSF);
        a = anew;
    }

    if (lane == 63) {
        out[b] = -(__logf(a + a64) + (float)e_total * 0.6931471805599453f);
    }
}

extern "C" void kernel_launch(void* const* d_in, const int* in_sizes, int n_in,
                              void* d_out, int out_size, void* d_ws, size_t ws_size,
                              hipStream_t stream) {
    const int*   y_true = (const int*)d_in[0];
    const float* y_pred = (const float*)d_in[1];
    float*       out    = (float*)d_out;

    const int B = out_size;   // output is [B,1]
    ctc_loss_kernel<<<B, 64, 0, stream>>>(y_true, y_pred, out);
}

// Round 8
// 194.437 us; speedup vs baseline: 1.0450x; 1.0020x over previous
//
#include <hip/hip_runtime.h>

// CTC batch cost (keras ctc_batch_cost semantics), forward only.
// B=512, T=512, C=128 (blank=127), L=32, S=65.
//
// Round-8: fwd/bwd split (r7 structure) + DOUBLE-PRECISION junction combine.
// r6/r7 failed with absmax=inf: the two halves are independently rescaled
// to O(1) at their own max, but fwd mass piles at HIGH states and rev mass
// at original LOW states; matched junction terms ~2^-136 flush to zero in
// f32 for some batch elements -> p=0 -> log -> inf. The junction dot-product
// is now computed in double (exponent range covers it), mantissa/exponent
// split by bit ops, exponent folded into the integer scale accumulator.
//
// Structure: block = 128 threads = 2 waves per batch element.
//   Wave 0: proven r5 alpha recursion, rows 0..255.
//   Wave 1: SAME alpha code on the time+label-reversed problem
//           (rows 511..256, labels reversed, states mirrored). CTC total
//           probability is invariant under this reversal.
// Junction at the 255->256 transition:
//   P = sum_{s2=0..64} abar(s2) * alpha'_255[64-s2]
//   abar(s2) = a + wshr1(a) + sg0*wshr1^2(a)  (group4's bracket),
//   abar(64) = a64 + a (lane 63).
// Identity hand-verified on an L=1,T=2 example (prefix/suffix/junction).

#define EPSF 1e-7f

constexpr int T_  = 512;
constexpr int C_  = 128;
constexpr int L_  = 32;
constexpr int PFG = 8;     // register prefetch depth (groups)

// lane j -> value of lane j-1; lane 0 -> 0.  (DPP wave_shr:1, bound_ctrl=0-fill)
__device__ __forceinline__ float wshr1(float x) {
    return __int_as_float(
        __builtin_amdgcn_mov_dpp(__float_as_int(x), 0x138, 0xf, 0xf, true));
}

// Exponent of strided wave max of v (lanes 3,7,...,63). Positive floats:
// int-max of bit patterns == bit pattern of float max; only exponent used.
// 27 = biased exponent of the 1e-30 dead-sample guard (self-corrects).
__device__ __forceinline__ int sample_eb(float v) {
    int mb = __builtin_amdgcn_readlane(__float_as_int(v), 3);
#pragma unroll
    for (int i = 1; i < 16; ++i) {
        const int t = __builtin_amdgcn_readlane(__float_as_int(v), 4 * i + 3);
        mb = (t > mb) ? t : mb;
    }
    const int eb = (int)((unsigned)mb >> 23);
    return (eb > 27) ? eb : 27;
}

__launch_bounds__(128)
__global__ void ctc_loss_kernel(const int* __restrict__ y_true,
                                const float* __restrict__ y_pred,
                                float* __restrict__ out) {
    __shared__ float shR[65];   // reversed wave's alpha'_255 (its states 0..64)
    __shared__ int   shE;       // reversed wave's exponent total

    const int b    = blockIdx.x;
    const int tid  = threadIdx.x;
    const int lane = tid & 63;
    const int w    = tid >> 6;   // 0 = forward, 1 = reversed

    const float* bb  = y_pred + (size_t)b * T_ * C_;
    const int*   lbl = y_true + b * L_;

    // Per-lane class & skip flag. Forward: state = lane over ext(labels).
    // Reversed: state = lane over ext(reversed labels); skip'(v)=skip(66-v).
    int   cls0 = C_ - 1;
    float sg0  = 0.f;
    if (w == 0) {
        if (lane & 1) cls0 = lbl[(lane - 1) >> 1];
        if ((lane & 1) && lane >= 3) {
            const int li = (lane - 1) >> 1;
            if (lbl[li] != lbl[li - 1]) sg0 = 1.f;
        }
    } else {
        if (lane & 1) cls0 = lbl[31 - ((lane - 1) >> 1)];
        if ((lane & 1) && lane >= 3) {
            const int li = (lane - 1) >> 1;
            if (lbl[31 - li] != lbl[32 - li]) sg0 = 1.f;
        }
    }

    // Recursion-time t (0..255) -> original row: fwd t, rev 511-t.
    auto rowp = [&](int t) {
        const int orig = w ? (511 - t) : t;
        return bb + (size_t)orig * C_ + cls0;
    };
    const int rs = w ? -C_ : C_;   // element stride for +1 recursion row

    // t=0 init (prob domain): states 0,1 = q(row0')[cls]+eps, rest 0.
    float a       = (lane < 2) ? (rowp(0)[0] + EPSF) : 0.f;
    float a64     = 0.f;   // state-64 sink, meaningful on lane 63 only
    int   e_total = 0;     // accumulated log2 scale (exact integer)

    auto loadQ = [&](float (&Pk)[4], int g) {
        const float* r = rowp(1 + 4 * g);
        Pk[0] = r[0]; Pk[1] = r[rs]; Pk[2] = r[2 * rs]; Pk[3] = r[3 * rs];
    };

    // Composed 4-row update, column-0 collapsed form (r5-proven).
    auto group4 = [&](const float (&P)[4]) {
        float x = a, z = a64;
#pragma unroll
        for (int r = 0; r < 4; ++r) {
            const float q  = P[r] + EPSF;
            const float qs = wshr1(q);      // blank-column value at lane 63
            const float x1 = wshr1(x);
            const float x2 = wshr1(x1);
            z = (z + x) * qs;               // state-64 sink (pre-update x)
            x = (x + x1 + sg0 * x2) * q;
        }
        a = x; a64 = z;
    };

    // Exact pow2 rescale from a previously-sampled exponent (r5-proven).
    auto scale = [&](int eb) {
        e_total += eb - 127;
        const float inv = __uint_as_float((unsigned)(254 - eb) << 23);  // 2^-e
        a *= inv; a64 *= inv;
    };

    // Prologue: prefetch PFG groups.
    float Q[PFG][4];
#pragma unroll
    for (int k = 0; k < PFG; ++k) loadQ(Q[k], k);
    int ebp = sample_eb(a);

    // Groups 0..47, refill to 55.
    for (int g0 = 0; g0 < 48; g0 += PFG) {
#pragma unroll
        for (int k = 0; k < PFG; ++k) {
            group4(Q[k]); scale(ebp); ebp = sample_eb(a);
            loadQ(Q[k], g0 + k + PFG);
        }
    }
    // Consume 48..55, refill 56..62 (7 groups).
#pragma unroll
    for (int k = 0; k < PFG; ++k) {
        group4(Q[k]); scale(ebp); ebp = sample_eb(a);
        if (k < 7) loadQ(Q[k], 56 + k);
    }
    // Tail-row loads (recursion rows 253..255).
    float qo[3];
#pragma unroll
    for (int r = 0; r < 3; ++r) qo[r] = rowp(253 + r)[0];
    // Consume 56..62.
#pragma unroll
    for (int k = 0; k < 7; ++k) {
        group4(Q[k]); scale(ebp);
        if (k < 6) ebp = sample_eb(a);
    }
    // Recursion rows 253..255, single steps (r5-proven; no rescale).
#pragma unroll
    for (int r = 0; r < 3; ++r) {
        const float p1 = wshr1(a);
        const float p2 = wshr1(p1);
        const float qb = wshr1(qo[r]);
        const float an = (a + p1 + sg0 * p2) * (qo[r] + EPSF);
        a64 = (a64 + a) * (qb + EPSF);
        a = an;
    }
    // Both waves now hold alpha after 256 rows (fwd: rows 0..255;
    // rev: rows 511..256 of the reversed problem).

    if (w == 1) {
        shR[lane] = a;                 // alpha'[state lane], states 0..63
        if (lane == 63) shR[64] = a64; // alpha'[64]
        if (lane == 0)  shE = e_total;
    }
    __syncthreads();

    if (w == 0) {
        // Pre-emission predecessor sum for target state s2 = lane.
        const float a1 = wshr1(a);
        const float a2 = wshr1(a1);
        const float abar = a + a1 + sg0 * a2;
        // P = sum_{s2} abar(s2) * alpha'[64 - s2] — in DOUBLE: the two
        // halves are independently normalized, matched terms can be ~2^-136.
        double p = (double)abar * (double)shR[64 - lane];
        if (lane == 63) p += (double)(a64 + a) * (double)shR[0];
        // Butterfly sum over 64 lanes.
#pragma unroll
        for (int m = 1; m < 64; m <<= 1) p += __shfl(p, lane ^ m);
        if (lane == 0) {
            if (p < 1e-300) p = 1e-300;            // guard (never hit in range)
            const unsigned long long bt = __double_as_longlong(p);
            const int k = (int)((bt >> 52) & 0x7FFULL) - 1023;
            const double mant = __longlong_as_double(
                (bt & 0x000FFFFFFFFFFFFFULL) | 0x3FF0000000000000ULL);  // [1,2)
            out[b] = -(__logf((float)mant) +
                       (float)(e_total + shE + k) * 0.6931471805599453f);
        }
    }
}

extern "C" void kernel_launch(void* const* d_in, const int* in_sizes, int n_in,
                              void* d_out, int out_size, void* d_ws, size_t ws_size,
                              hipStream_t stream) {
    const int*   y_true = (const int*)d_in[0];
    const float* y_pred = (const float*)d_in[1];
    float*       out    = (float*)d_out;

    const int B = out_size;   // output is [B,1]
    ctc_loss_kernel<<<B, 128, 0, stream>>>(y_true, y_pred, out);
}

// Round 9
// 191.812 us; speedup vs baseline: 1.0593x; 1.0137x over previous
//
#include <hip/hip_runtime.h>

// CTC batch cost (keras ctc_batch_cost semantics), forward only.
// B=512, T=512, C=128 (blank=127), L=32, S=65.
//
// Round-9: r8 fwd/bwd-split algorithm, MINIMAL CODE FOOTPRINT build.
// Evidence: r3/r4/r5/r8 all land at kernel ~58-70us despite removing LDS,
// shuffles, 40% of VALU, and HALF the sequential depth (r8). Per-wave work
// is not the wall. Hypothesis: fully-unrolled group loops produce 40-80 KB
// of straight-line code (> 32KB I$), and the harness's 512 MiB poison fill
// evicts L2/L3 code lines every iteration -> waves stall on instruction
// fetch (invisible in SQ counters, invariant to data-path changes).
// This build: PFG=4, main loop ROLLED (unroll(disable), runtime g, clamped
// refill), only 3-group+3-row tail unrolled. Hot loop ~3 KB, kernel ~6 KB.
// Per-group math order byte-identical to r8 (absmax must stay 4.0).
//
// Structure: block = 128 threads = 2 waves per batch element.
//   Wave 0: alpha recursion rows 0..255; wave 1: same code on the
//   time+label-reversed problem (rows 511..256). Junction (double prec):
//   P = sum_{s2} abar(s2) * alpha'[64-s2], abar = a + a>>1 + sg0*(a>>2),
//   abar(64) = a64 + a. Exponents add; mantissa/exponent split for logf.

#define EPSF 1e-7f

constexpr int C_  = 128;
constexpr int L_  = 32;
constexpr int PFG = 4;     // register prefetch depth (groups)

// lane j -> value of lane j-1; lane 0 -> 0.  (DPP wave_shr:1, bound_ctrl=0-fill)
__device__ __forceinline__ float wshr1(float x) {
    return __int_as_float(
        __builtin_amdgcn_mov_dpp(__float_as_int(x), 0x138, 0xf, 0xf, true));
}

// Exponent of strided wave max of v (lanes 3,7,...,63). Positive floats:
// int-max of bit patterns == bit pattern of float max; only exponent used.
// 27 = biased exponent of the 1e-30 dead-sample guard (self-corrects).
__device__ __forceinline__ int sample_eb(float v) {
    int mb = __builtin_amdgcn_readlane(__float_as_int(v), 3);
#pragma unroll
    for (int i = 1; i < 16; ++i) {
        const int t = __builtin_amdgcn_readlane(__float_as_int(v), 4 * i + 3);
        mb = (t > mb) ? t : mb;
    }
    const int eb = (int)((unsigned)mb >> 23);
    return (eb > 27) ? eb : 27;
}

__launch_bounds__(128)
__global__ void ctc_loss_kernel(const int* __restrict__ y_true,
                                const float* __restrict__ y_pred,
                                float* __restrict__ out) {
    __shared__ float shR[65];   // reversed wave's alpha' (its states 0..64)
    __shared__ int   shE;       // reversed wave's exponent total

    const int b    = blockIdx.x;
    const int tid  = threadIdx.x;
    const int lane = tid & 63;
    const int w    = tid >> 6;   // 0 = forward, 1 = reversed

    const float* bb  = y_pred + (size_t)b * 512 * C_;
    const int*   lbl = y_true + b * L_;

    // Per-lane class & skip flag. Forward: state = lane over ext(labels).
    // Reversed: state = lane over ext(reversed labels); skip'(v)=skip(66-v).
    int   cls0 = C_ - 1;
    float sg0  = 0.f;
    if (w == 0) {
        if (lane & 1) cls0 = lbl[(lane - 1) >> 1];
        if ((lane & 1) && lane >= 3) {
            const int li = (lane - 1) >> 1;
            if (lbl[li] != lbl[li - 1]) sg0 = 1.f;
        }
    } else {
        if (lane & 1) cls0 = lbl[31 - ((lane - 1) >> 1)];
        if ((lane & 1) && lane >= 3) {
            const int li = (lane - 1) >> 1;
            if (lbl[31 - li] != lbl[32 - li]) sg0 = 1.f;
        }
    }

    // Recursion-time t (0..255) -> original row: fwd t, rev 511-t.
    auto rowp = [&](int t) {
        const int orig = w ? (511 - t) : t;
        return bb + (size_t)orig * C_ + cls0;
    };
    const int rs = w ? -C_ : C_;   // element stride for +1 recursion row

    // t=0 init (prob domain): states 0,1 = q(row0')[cls]+eps, rest 0.
    float a       = (lane < 2) ? (rowp(0)[0] + EPSF) : 0.f;
    float a64     = 0.f;   // state-64 sink, meaningful on lane 63 only
    int   e_total = 0;     // accumulated log2 scale (exact integer)

    auto loadQ = [&](float (&Pk)[4], int g) {
        const float* r = rowp(1 + 4 * g);
        Pk[0] = r[0]; Pk[1] = r[rs]; Pk[2] = r[2 * rs]; Pk[3] = r[3 * rs];
    };

    // Composed 4-row update, column-0 collapsed form (r5-proven).
    auto group4 = [&](const float (&P)[4]) {
        float x = a, z = a64;
#pragma unroll
        for (int r = 0; r < 4; ++r) {
            const float q  = P[r] + EPSF;
            const float qs = wshr1(q);      // blank-column value at lane 63
            const float x1 = wshr1(x);
            const float x2 = wshr1(x1);
            z = (z + x) * qs;               // state-64 sink (pre-update x)
            x = (x + x1 + sg0 * x2) * q;
        }
        a = x; a64 = z;
    };

    // Exact pow2 rescale from a previously-sampled exponent (r5-proven).
    auto scale = [&](int eb) {
        e_total += eb - 127;
        const float inv = __uint_as_float((unsigned)(254 - eb) << 23);  // 2^-e
        a *= inv; a64 *= inv;
    };

    // Prologue: prefetch PFG groups (groups 0..3).
    float Q[PFG][4];
#pragma unroll
    for (int k = 0; k < PFG; ++k) loadQ(Q[k], k);
    int ebp = sample_eb(a);

    // Main loop: groups 0..59, ROLLED (15 x 4). Refill group g+4, clamped to
    // 62 (clamped refills are junk-but-in-range, never consumed). After the
    // loop Q[0..2] hold groups 60..62.
#pragma clang loop unroll(disable)
    for (int gq = 0; gq < 15; ++gq) {
#pragma unroll
        for (int k = 0; k < PFG; ++k) {
            group4(Q[k]);
            scale(ebp);
            ebp = sample_eb(a);
            int gn = gq * PFG + k + PFG;
            if (gn > 62) gn = 62;
            loadQ(Q[k], gn);
        }
    }

    // Tail-row loads (recursion rows 253..255), issued before the tail groups.
    float qo[3];
#pragma unroll
    for (int r = 0; r < 3; ++r) qo[r] = rowp(253 + r)[0];

    // Groups 60..62.
#pragma unroll
    for (int k = 0; k < 3; ++k) {
        group4(Q[k]);
        scale(ebp);
        if (k < 2) ebp = sample_eb(a);
    }

    // Recursion rows 253..255, single steps (no rescale).
#pragma unroll
    for (int r = 0; r < 3; ++r) {
        const float p1 = wshr1(a);
        const float p2 = wshr1(p1);
        const float qb = wshr1(qo[r]);
        const float an = (a + p1 + sg0 * p2) * (qo[r] + EPSF);
        a64 = (a64 + a) * (qb + EPSF);
        a = an;
    }
    // Both waves now hold alpha after 256 rows (fwd: rows 0..255;
    // rev: rows 511..256 of the reversed problem).

    if (w == 1) {
        shR[lane] = a;                 // alpha'[state lane], states 0..63
        if (lane == 63) shR[64] = a64; // alpha'[64]
        if (lane == 0)  shE = e_total;
    }
    __syncthreads();

    if (w == 0) {
        // Pre-emission predecessor sum for target state s2 = lane.
        const float a1 = wshr1(a);
        const float a2 = wshr1(a1);
        const float abar = a + a1 + sg0 * a2;
        // Junction dot-product in DOUBLE: halves are independently
        // normalized; matched terms can be ~2^-136 (f32 flushes -> inf bug).
        double p = (double)abar * (double)shR[64 - lane];
        if (lane == 63) p += (double)(a64 + a) * (double)shR[0];
#pragma unroll
        for (int m = 1; m < 64; m <<= 1) p += __shfl(p, lane ^ m);
        if (lane == 0) {
            if (p < 1e-300) p = 1e-300;            // guard (never hit in range)
            const unsigned long long bt = __double_as_longlong(p);
            const int k = (int)((bt >> 52) & 0x7FFULL) - 1023;
            const double mant = __longlong_as_double(
                (bt & 0x000FFFFFFFFFFFFFULL) | 0x3FF0000000000000ULL);  // [1,2)
            out[b] = -(__logf((float)mant) +
                       (float)(e_total + shE + k) * 0.6931471805599453f);
        }
    }
}

extern "C" void kernel_launch(void* const* d_in, const int* in_sizes, int n_in,
                              void* d_out, int out_size, void* d_ws, size_t ws_size,
                              hipStream_t stream) {
    const int*   y_true = (const int*)d_in[0];
    const float* y_pred = (const float*)d_in[1];
    float*       out    = (float*)d_out;

    const int B = out_size;   // output is [B,1]
    ctc_loss_kernel<<<B, 128, 0, stream>>>(y_true, y_pred, out);
}